// Round 1
// baseline (72.586 us; speedup 1.0000x reference)
//
#include <hip/hip_runtime.h>

static __device__ __forceinline__ unsigned umax2(unsigned a, unsigned b) { return a > b ? a : b; }

// One block = 4 waves. One wave = 8 batches = 16 determinants.
// Within a wave: 16 groups of 4 lanes; group g handles det g
// (batch = g>>1, half: g&1 ? down : up). Lane q of a group owns rows 4q..4q+3.
__global__ __launch_bounds__(256) void slater_det_kernel(
    const float* __restrict__ cfg,
    const float* __restrict__ sup,
    const float* __restrict__ sdn,
    float* __restrict__ out)
{
    __shared__ __align__(16) int idx_lds[4][16][16];
    __shared__ float det_lds[4][16];

    const int tid  = threadIdx.x;
    const int wave = tid >> 6;
    const int lane = tid & 63;
    const int wb0  = (blockIdx.x * 4 + wave) * 8;   // first batch of this wave

    // ---------------- Phase 1: extract sorted indices of the ones ----------------
    // Pass d covers batch wb0+(d>>1), half (d&1): 256 floats across 64 lanes x4.
    float4 c[16];
#pragma unroll
    for (int d = 0; d < 16; ++d) {
        const float* p = cfg + (size_t)(wb0 + (d >> 1)) * 512
                             + (size_t)(d & 1) * 256 + (size_t)lane * 4;
        c[d] = *(const float4*)p;
    }
    const unsigned long long lt = (1ull << lane) - 1ull;   // bits of lanes below us
#pragma unroll
    for (int d = 0; d < 16; ++d) {
        float4 v = c[d];
        bool n0 = v.x != 0.f, n1 = v.y != 0.f, n2 = v.z != 0.f, n3 = v.w != 0.f;
        unsigned long long b0 = __ballot(n0);
        unsigned long long b1 = __ballot(n1);
        unsigned long long b2 = __ballot(n2);
        unsigned long long b3 = __ballot(n3);
        // rank = number of set positions strictly before position 4*lane+j
        int base = __popcll(b0 & lt) + __popcll(b1 & lt)
                 + __popcll(b2 & lt) + __popcll(b3 & lt);
        int pos = lane * 4;
        int r = base;
        if (n0 && r < 16) idx_lds[wave][d][r] = pos;
        r += n0;
        if (n1 && r < 16) idx_lds[wave][d][r] = pos + 1;
        r += n1;
        if (n2 && r < 16) idx_lds[wave][d][r] = pos + 2;
        r += n2;
        if (n3 && r < 16) idx_lds[wave][d][r] = pos + 3;
    }
    __syncthreads();

    // ---------------- Phase 2: gather rows + Gaussian elimination ----------------
    const int g = lane >> 2;   // det id within wave
    const int q = lane & 3;    // sub-lane within group
    const int4 ri = *(const int4*)&idx_lds[wave][g][q * 4];
    const float* tab = (g & 1) ? sdn : sup;

    float rr[4][16];
    const int rid[4] = {ri.x, ri.y, ri.z, ri.w};
#pragma unroll
    for (int j = 0; j < 4; ++j) {
        const float* p = tab + (size_t)rid[j] * 16;
        float4 a = *(const float4*)(p + 0);
        float4 b = *(const float4*)(p + 4);
        float4 e = *(const float4*)(p + 8);
        float4 f = *(const float4*)(p + 12);
        rr[j][0]=a.x;  rr[j][1]=a.y;  rr[j][2]=a.z;  rr[j][3]=a.w;
        rr[j][4]=b.x;  rr[j][5]=b.y;  rr[j][6]=b.z;  rr[j][7]=b.w;
        rr[j][8]=e.x;  rr[j][9]=e.y;  rr[j][10]=e.z; rr[j][11]=e.w;
        rr[j][12]=f.x; rr[j][13]=f.y; rr[j][14]=f.z; rr[j][15]=f.w;
    }

    // Virtual partial pivoting: no physical row swaps (avoids dynamic VGPR
    // indexing). Active-row mask per lane; pivot chosen by packed uint key
    // (|value| bits | global row index). Sign accumulated via Lehmer counts.
    unsigned am = 0xFu;
    float det = 1.f;
    int flips = 0;

#pragma unroll
    for (int k = 0; k < 16; ++k) {
        unsigned a0 = (__float_as_uint(rr[0][k]) & 0x7FFFFFF0u) | (unsigned)(q*4+0);
        unsigned a1 = (__float_as_uint(rr[1][k]) & 0x7FFFFFF0u) | (unsigned)(q*4+1);
        unsigned a2 = (__float_as_uint(rr[2][k]) & 0x7FFFFFF0u) | (unsigned)(q*4+2);
        unsigned a3 = (__float_as_uint(rr[3][k]) & 0x7FFFFFF0u) | (unsigned)(q*4+3);
        unsigned key0 = (am & 1u) ? a0 : (unsigned)(q*4+0);   // dead rows: index-only key
        unsigned key1 = (am & 2u) ? a1 : (unsigned)(q*4+1);
        unsigned key2 = (am & 4u) ? a2 : (unsigned)(q*4+2);
        unsigned key3 = (am & 8u) ? a3 : (unsigned)(q*4+3);
        unsigned kloc = umax2(umax2(key0, key1), umax2(key2, key3));
        int jloc = (int)(kloc & 3u);
        // speculatively select this lane's best row (static-index cndmask tree)
        float crow[16];
#pragma unroll
        for (int cc = k; cc < 16; ++cc) {
            float t01 = (jloc & 1) ? rr[1][cc] : rr[0][cc];
            float t23 = (jloc & 1) ? rr[3][cc] : rr[2][cc];
            crow[cc] = (jloc & 2) ? t23 : t01;
        }
        // group argmax over 4 lanes
        unsigned ko = kloc;
        ko = umax2(ko, (unsigned)__shfl_xor((int)ko, 1));
        ko = umax2(ko, (unsigned)__shfl_xor((int)ko, 2));
        int p   = (int)(ko & 15u);          // winning global row index
        int src = (lane & ~3) | (p >> 2);   // owner lane (its crow == winner row)
        // broadcast pivot row
        float prow[16];
#pragma unroll
        for (int cc = k; cc < 16; ++cc) prow[cc] = __shfl(crow[cc], src);
        float piv = prow[k];
        det *= piv;
        // Lehmer digit: # active rows with index < p (parity of permutation)
        int t = p - q * 4;
        unsigned mlt = (t <= 0) ? 0u : ((t >= 4) ? 0xFu : ((1u << t) - 1u));
        int cnt = __popc(am & mlt);
        cnt += __shfl_xor(cnt, 1);
        cnt += __shfl_xor(cnt, 2);
        flips += cnt;
        if (q == (p >> 2)) am &= ~(1u << (p & 3));
        // eliminate column k from all rows (dead rows evolve garbage -- never
        // read: their keys are masked and they're never broadcast)
        float inv = 1.0f / piv;
        float f0 = rr[0][k] * inv;
        float f1 = rr[1][k] * inv;
        float f2 = rr[2][k] * inv;
        float f3 = rr[3][k] * inv;
#pragma unroll
        for (int cc = k + 1; cc < 16; ++cc) {
            rr[0][cc] = __builtin_fmaf(-f0, prow[cc], rr[0][cc]);
            rr[1][cc] = __builtin_fmaf(-f1, prow[cc], rr[1][cc]);
            rr[2][cc] = __builtin_fmaf(-f2, prow[cc], rr[2][cc]);
            rr[3][cc] = __builtin_fmaf(-f3, prow[cc], rr[3][cc]);
        }
    }
    float result = (flips & 1) ? -det : det;

    if (q == 0) det_lds[wave][g] = result;
    __syncthreads();
    if (lane < 8) {
        out[wb0 + lane] = det_lds[wave][2 * lane] * det_lds[wave][2 * lane + 1];
    }
}

extern "C" void kernel_launch(void* const* d_in, const int* in_sizes, int n_in,
                              void* d_out, int out_size, void* d_ws, size_t ws_size,
                              hipStream_t stream) {
    const float* cfg = (const float*)d_in[0];
    const float* sup = (const float*)d_in[1];
    const float* sdn = (const float*)d_in[2];
    float* outp = (float*)d_out;
    const int B = in_sizes[0] / 512;          // 131072
    const int blocks = B / 32;                // 8 batches/wave * 4 waves/block
    slater_det_kernel<<<blocks, 256, 0, stream>>>(cfg, sup, sdn, outp);
}